// Round 1
// baseline (2779.066 us; speedup 1.0000x reference)
//
#include <hip/hip_runtime.h>
#include <hip/hip_bf16.h>

#define B_ 2
#define S_ 2048
#define D_ 1024
#define H_ 16
#define KV_ 4
#define HD_ 64
#define G_ (H_ / KV_)

typedef __attribute__((ext_vector_type(8))) short short8;
typedef __attribute__((ext_vector_type(4))) float floatx4;

// ---------------- fp32 -> bf16 convert ----------------
__global__ void cvt_bf16_kernel(const float* __restrict__ in,
                                __hip_bfloat16* __restrict__ out, int n) {
    int i = blockIdx.x * blockDim.x + threadIdx.x;
    if (i < n) out[i] = __float2bfloat16(in[i]);
}

// ---------------- NT GEMM: C(MxN) f32 = A(MxK) * B(NxK)^T, bf16 inputs ----------------
// block = 256 threads (4 waves, 2x2), block tile 128x128, wave tile 64x64
// via 4x4 of v_mfma_f32_16x16x32_bf16. Direct-from-global (round 0 baseline).
__global__ __launch_bounds__(256) void gemm_bt_kernel(const short* __restrict__ A,
                                                      const short* __restrict__ Bm,
                                                      float* __restrict__ C,
                                                      int M, int N, int K) {
    int tid = threadIdx.x;
    int wid = tid >> 6, lane = tid & 63;
    int wr = wid >> 1, wc = wid & 1;
    long m_base = (long)blockIdx.y * 128 + wr * 64;
    long n_base = (long)blockIdx.x * 128 + wc * 64;
    int r = lane & 15, kq = lane >> 4;

    floatx4 acc[4][4];
#pragma unroll
    for (int i = 0; i < 4; ++i)
#pragma unroll
        for (int j = 0; j < 4; ++j) acc[i][j] = {0.f, 0.f, 0.f, 0.f};

    for (int k0 = 0; k0 < K; k0 += 32) {
        short8 a[4], b[4];
#pragma unroll
        for (int mi = 0; mi < 4; ++mi)
            a[mi] = *(const short8*)(A + (m_base + mi * 16 + r) * K + k0 + kq * 8);
#pragma unroll
        for (int ni = 0; ni < 4; ++ni)
            b[ni] = *(const short8*)(Bm + (n_base + ni * 16 + r) * K + k0 + kq * 8);
#pragma unroll
        for (int mi = 0; mi < 4; ++mi)
#pragma unroll
            for (int ni = 0; ni < 4; ++ni)
                acc[mi][ni] = __builtin_amdgcn_mfma_f32_16x16x32_bf16(
                    a[mi], b[ni], acc[mi][ni], 0, 0, 0);
    }
    // C/D layout (measured m89/m91): col = lane&15, row = (lane>>4)*4 + j
    int col_l = lane & 15, row_l = (lane >> 4) * 4;
#pragma unroll
    for (int mi = 0; mi < 4; ++mi)
#pragma unroll
        for (int ni = 0; ni < 4; ++ni) {
            long col = n_base + ni * 16 + col_l;
            long row0 = m_base + mi * 16 + row_l;
#pragma unroll
            for (int j = 0; j < 4; ++j)
                C[(row0 + j) * N + col] = acc[mi][ni][j];
        }
}

// ---------------- RMSNorm (per-64) + RoPE, in place ----------------
// buf: nvec vectors of 64 f32. gw enumerates (token, head, half).
__global__ void norm_rope_kernel(float* __restrict__ buf,
                                 const float* __restrict__ freqs,
                                 const float* __restrict__ w, int nvec, int nh) {
    int gt = blockIdx.x * blockDim.x + threadIdx.x;
    int gw = gt >> 6;
    int lane = gt & 63;
    if (gw >= nvec) return;
    int t = gw / (nh * 2);      // token index (b*S + s)
    int s = t & (S_ - 1);       // position in sequence
    float* v = buf + (long)gw * 64;
    float x = v[lane];
    float ss = x * x;
#pragma unroll
    for (int off = 32; off; off >>= 1) ss += __shfl_xor(ss, off);
    float r = rsqrtf(ss * (1.f / 64.f) + 1e-6f);
    x = x * r * w[lane];
    // RoPE: pairs (even, odd) with freqs[s][lane>>1]
    int i = lane >> 1;
    float c  = freqs[(s * (HD_ / 2) + i) * 2];
    float sn = freqs[(s * (HD_ / 2) + i) * 2 + 1];
    float p = __shfl_xor(x, 1);
    float y = (lane & 1) ? fmaf(p, sn, x * c) : fmaf(x, c, -(p * sn));
    v[lane] = y;
}

// ---------------- differential causal attention (fp32 flash) ----------------
// grid (S/4, H, B), block 256 = 4 waves; wave w owns q-row = blockIdx.x*4 + w.
// Two online-softmax states (attn1, attn2); out = O1/l1 - lambda*O2/l2.
__global__ __launch_bounds__(256) void attn_kernel(const float* __restrict__ qbuf,
                                                   const float* __restrict__ kbuf,
                                                   const float* __restrict__ vbuf,
                                                   float* __restrict__ obuf,
                                                   const float* __restrict__ lam_p) {
    __shared__ float k1s[64][65];   // +1 pad: 2-way bank aliasing only (free)
    __shared__ float k2s[64][65];
    __shared__ float vs[64][65];
    __shared__ float qs[4][128];
    __shared__ float p1s[4][64];
    __shared__ float p2s[4][64];

    int tid = threadIdx.x, wid = tid >> 6, lane = tid & 63;
    int b = blockIdx.z, h = blockIdx.y;
    int q = blockIdx.x * 4 + wid;
    int kv = h / G_;
    float lam = lam_p[0];

    const float* qrow = qbuf + ((long)(b * S_ + q) * H_ + h) * 128;
    qs[wid][lane] = qrow[lane];
    qs[wid][lane + 64] = qrow[lane + 64];

    float acc1 = 0.f, acc2 = 0.f;
    float m1 = -1e30f, l1 = 0.f, m2 = -1e30f, l2 = 0.f;
    int kend = blockIdx.x * 4 + 3;
    const float scale = 0.125f;   // 1/sqrt(64)

    for (int kb = 0; kb <= kend; kb += 64) {
        __syncthreads();
        // cooperative tile load: 64 rows x 64 cols of k1,k2,v
#pragma unroll
        for (int it = 0; it < 16; ++it) {
            int idx = it * 256 + tid;
            int rr = idx >> 6, cc = idx & 63;
            long base = ((long)(b * S_ + kb + rr) * KV_ + kv);
            k1s[rr][cc] = kbuf[base * 128 + cc];
            k2s[rr][cc] = kbuf[base * 128 + 64 + cc];
            vs[rr][cc]  = vbuf[base * 64 + cc];
        }
        __syncthreads();

        // lane j scores k = kb + j
        float s1 = 0.f, s2 = 0.f;
#pragma unroll 16
        for (int d = 0; d < 64; ++d) {
            s1 += qs[wid][d] * k1s[lane][d];
            s2 += qs[wid][d + 64] * k2s[lane][d];
        }
        s1 *= scale; s2 *= scale;
        s1 = 50.f * tanhf(s1 * 0.02f);   // soft-cap
        s2 = 50.f * tanhf(s2 * 0.02f);
        int kk = kb + lane;
        bool valid = kk <= q;
        float e1 = valid ? s1 : -1e30f;
        float e2 = valid ? s2 : -1e30f;
        float t1 = e1, t2 = e2;
#pragma unroll
        for (int off = 32; off; off >>= 1) {
            t1 = fmaxf(t1, __shfl_xor(t1, off));
            t2 = fmaxf(t2, __shfl_xor(t2, off));
        }
        float nm1 = fmaxf(m1, t1), nm2 = fmaxf(m2, t2);
        float c1 = __expf(m1 - nm1), c2 = __expf(m2 - nm2);
        float p1 = valid ? __expf(e1 - nm1) : 0.f;
        float p2 = valid ? __expf(e2 - nm2) : 0.f;
        float sp1 = p1, sp2 = p2;
#pragma unroll
        for (int off = 32; off; off >>= 1) {
            sp1 += __shfl_xor(sp1, off);
            sp2 += __shfl_xor(sp2, off);
        }
        m1 = nm1; m2 = nm2;
        l1 = l1 * c1 + sp1;
        l2 = l2 * c2 + sp2;
        p1s[wid][lane] = p1;
        p2s[wid][lane] = p2;
        __syncthreads();
        acc1 *= c1; acc2 *= c2;
#pragma unroll 8
        for (int k = 0; k < 64; ++k) {
            float vv = vs[k][lane];
            acc1 = fmaf(p1s[wid][k], vv, acc1);
            acc2 = fmaf(p2s[wid][k], vv, acc2);
        }
    }
    float out = acc1 / l1 - lam * (acc2 / l2);
    obuf[((long)(b * S_ + q) * H_ + h) * 64 + lane] = out;
}

// ---------------- launch ----------------
extern "C" void kernel_launch(void* const* d_in, const int* in_sizes, int n_in,
                              void* d_out, int out_size, void* d_ws, size_t ws_size,
                              hipStream_t stream) {
    const float* x     = (const float*)d_in[0];
    const float* freqs = (const float*)d_in[1];
    const float* wq    = (const float*)d_in[2];
    const float* wk    = (const float*)d_in[3];
    const float* wv    = (const float*)d_in[4];
    const float* wo    = (const float*)d_in[5];
    const float* qnw   = (const float*)d_in[6];
    const float* knw   = (const float*)d_in[7];
    const float* lam   = (const float*)d_in[8];
    float* out = (float*)d_out;

    const int T = B_ * S_;              // 4096 tokens
    char* ws = (char*)d_ws;
    size_t off = 0;
    auto alloc = [&](size_t bytes) {
        void* p = ws + off;
        off += (bytes + 255) & ~(size_t)255;
        return p;
    };
    __hip_bfloat16* xb  = (__hip_bfloat16*)alloc((size_t)T * D_ * 2);
    __hip_bfloat16* wqb = (__hip_bfloat16*)alloc((size_t)2 * H_ * HD_ * D_ * 2);
    __hip_bfloat16* wkb = (__hip_bfloat16*)alloc((size_t)2 * KV_ * HD_ * D_ * 2);
    __hip_bfloat16* wvb = (__hip_bfloat16*)alloc((size_t)KV_ * HD_ * D_ * 2);
    __hip_bfloat16* wob = (__hip_bfloat16*)alloc((size_t)D_ * H_ * HD_ * 2);
    float* qf = (float*)alloc((size_t)T * 2 * H_ * HD_ * 4);
    float* kf = (float*)alloc((size_t)T * 2 * KV_ * HD_ * 4);
    float* vf = (float*)alloc((size_t)T * KV_ * HD_ * 4);
    float* ao = (float*)alloc((size_t)T * H_ * HD_ * 4);
    __hip_bfloat16* aob = (__hip_bfloat16*)alloc((size_t)T * H_ * HD_ * 2);

    auto cvt = [&](const float* src, __hip_bfloat16* dst, int n) {
        cvt_bf16_kernel<<<(n + 255) / 256, 256, 0, stream>>>(src, dst, n);
    };
    cvt(x, xb, T * D_);
    cvt(wq, wqb, 2 * H_ * HD_ * D_);
    cvt(wk, wkb, 2 * KV_ * HD_ * D_);
    cvt(wv, wvb, KV_ * HD_ * D_);
    cvt(wo, wob, D_ * H_ * HD_);

    // projections
    gemm_bt_kernel<<<dim3((2 * H_ * HD_) / 128, T / 128), 256, 0, stream>>>(
        (const short*)xb, (const short*)wqb, qf, T, 2 * H_ * HD_, D_);
    gemm_bt_kernel<<<dim3((2 * KV_ * HD_) / 128, T / 128), 256, 0, stream>>>(
        (const short*)xb, (const short*)wkb, kf, T, 2 * KV_ * HD_, D_);
    gemm_bt_kernel<<<dim3((KV_ * HD_) / 128, T / 128), 256, 0, stream>>>(
        (const short*)xb, (const short*)wvb, vf, T, KV_ * HD_, D_);

    // QK-norm + RoPE
    {
        int nvq = T * H_ * 2;
        norm_rope_kernel<<<(nvq * 64 + 255) / 256, 256, 0, stream>>>(qf, freqs, qnw, nvq, H_);
        int nvk = T * KV_ * 2;
        norm_rope_kernel<<<(nvk * 64 + 255) / 256, 256, 0, stream>>>(kf, freqs, knw, nvk, KV_);
    }

    // differential causal attention
    attn_kernel<<<dim3(S_ / 4, H_, B_), 256, 0, stream>>>(qf, kf, vf, ao, lam);

    // output projection
    cvt(ao, aob, T * H_ * HD_);
    gemm_bt_kernel<<<dim3(D_ / 128, T / 128), 256, 0, stream>>>(
        (const short*)aob, (const short*)wob, out, T, D_, D_);
}

// Round 2
// 475.952 us; speedup vs baseline: 5.8390x; 5.8390x over previous
//
#include <hip/hip_runtime.h>
#include <hip/hip_bf16.h>

#define B_ 2
#define S_ 2048
#define D_ 1024
#define H_ 16
#define KV_ 4
#define HD_ 64
#define G_ (H_ / KV_)

typedef __attribute__((ext_vector_type(8))) short short8;
typedef __attribute__((ext_vector_type(4))) float floatx4;

// ---------------- fp32 -> bf16 convert ----------------
__global__ void cvt_bf16_kernel(const float* __restrict__ in,
                                __hip_bfloat16* __restrict__ out, int n) {
    int i = blockIdx.x * blockDim.x + threadIdx.x;
    if (i < n) out[i] = __float2bfloat16(in[i]);
}

// ---------------- NT GEMM: C(MxN) f32 = A(MxK) * B(NxK)^T, bf16 inputs ----------------
__global__ __launch_bounds__(256) void gemm_bt_kernel(const short* __restrict__ A,
                                                      const short* __restrict__ Bm,
                                                      float* __restrict__ C,
                                                      int M, int N, int K) {
    int tid = threadIdx.x;
    int wid = tid >> 6, lane = tid & 63;
    int wr = wid >> 1, wc = wid & 1;
    long m_base = (long)blockIdx.y * 128 + wr * 64;
    long n_base = (long)blockIdx.x * 128 + wc * 64;
    int r = lane & 15, kq = lane >> 4;

    floatx4 acc[4][4];
#pragma unroll
    for (int i = 0; i < 4; ++i)
#pragma unroll
        for (int j = 0; j < 4; ++j) acc[i][j] = {0.f, 0.f, 0.f, 0.f};

    for (int k0 = 0; k0 < K; k0 += 32) {
        short8 a[4], b[4];
#pragma unroll
        for (int mi = 0; mi < 4; ++mi)
            a[mi] = *(const short8*)(A + (m_base + mi * 16 + r) * K + k0 + kq * 8);
#pragma unroll
        for (int ni = 0; ni < 4; ++ni)
            b[ni] = *(const short8*)(Bm + (n_base + ni * 16 + r) * K + k0 + kq * 8);
#pragma unroll
        for (int mi = 0; mi < 4; ++mi)
#pragma unroll
            for (int ni = 0; ni < 4; ++ni)
                acc[mi][ni] = __builtin_amdgcn_mfma_f32_16x16x32_bf16(
                    a[mi], b[ni], acc[mi][ni], 0, 0, 0);
    }
    int col_l = lane & 15, row_l = (lane >> 4) * 4;
#pragma unroll
    for (int mi = 0; mi < 4; ++mi)
#pragma unroll
        for (int ni = 0; ni < 4; ++ni) {
            long col = n_base + ni * 16 + col_l;
            long row0 = m_base + mi * 16 + row_l;
#pragma unroll
            for (int j = 0; j < 4; ++j)
                C[(row0 + j) * N + col] = acc[mi][ni][j];
        }
}

// ---------------- RMSNorm (per-64) + RoPE, f32 in -> bf16 out ----------------
__global__ void norm_rope_kernel(const float* __restrict__ buf,
                                 __hip_bfloat16* __restrict__ outb,
                                 const float* __restrict__ freqs,
                                 const float* __restrict__ w, int nvec, int nh) {
    int gt = blockIdx.x * blockDim.x + threadIdx.x;
    int gw = gt >> 6;
    int lane = gt & 63;
    if (gw >= nvec) return;
    int t = gw / (nh * 2);
    int s = t & (S_ - 1);
    const float* v = buf + (long)gw * 64;
    float x = v[lane];
    float ss = x * x;
#pragma unroll
    for (int off = 32; off; off >>= 1) ss += __shfl_xor(ss, off);
    float r = rsqrtf(ss * (1.f / 64.f) + 1e-6f);
    x = x * r * w[lane];
    int i = lane >> 1;
    float c  = freqs[(s * (HD_ / 2) + i) * 2];
    float sn = freqs[(s * (HD_ / 2) + i) * 2 + 1];
    float p = __shfl_xor(x, 1);
    float y = (lane & 1) ? fmaf(p, sn, x * c) : fmaf(x, c, -(p * sn));
    outb[(long)gw * 64 + lane] = __float2bfloat16(y);
}

// ---------------- differential causal attention (MFMA flash, fixed-offset softmax) ----------------
// grid (S/64, H, B), block 256 = 4 waves; wave w owns q rows [qb*64+w*16, +16).
// Soft-cap bounds scores to |s|<=8 (RMSNorm rows have norm 8), so softmax uses a
// FIXED offset M=12: no online max tracking, no rescale. out = O1/l1 - lam*O2/l2.
__global__ __launch_bounds__(256) void attn_kernel(const short* __restrict__ qb,
                                                   const short* __restrict__ kbuf,
                                                   const short* __restrict__ vbuf,
                                                   __hip_bfloat16* __restrict__ ob,
                                                   const float* __restrict__ lam_p) {
    __shared__ short k1s[64][72];   // K half-1 tile, row-major (pad->2-way alias only)
    __shared__ short k2s[64][72];   // K half-2 tile
    __shared__ short vts[64][72];   // V tile TRANSPOSED: vts[d][k]
    __shared__ short pls[4][16][72];// per-wave P buffer (wave-private, no barrier)

    int tid = threadIdx.x, w = tid >> 6, lane = tid & 63;
    int b = blockIdx.z, h = blockIdx.y, kv = h / G_;
    int q0 = blockIdx.x * 64 + w * 16;
    int r = lane & 15, kq = lane >> 4;
    float lam = lam_p[0];

    // Q fragments: qa[map][kstep]; lane holds q-row q0+r, k-elems kq*8..+7
    short8 qa[2][2];
    {
        const short* qrow = qb + ((long)(b * S_ + q0 + r) * H_ + h) * 128;
        qa[0][0] = *(const short8*)(qrow + kq * 8);
        qa[0][1] = *(const short8*)(qrow + 32 + kq * 8);
        qa[1][0] = *(const short8*)(qrow + 64 + kq * 8);
        qa[1][1] = *(const short8*)(qrow + 96 + kq * 8);
    }

    floatx4 acc[2][4];   // [map][d-tile] output accumulators (16 q x 64 d per wave)
#pragma unroll
    for (int m = 0; m < 2; ++m)
#pragma unroll
        for (int dt = 0; dt < 4; ++dt) acc[m][dt] = {0.f, 0.f, 0.f, 0.f};
    float lp[2][4] = {{0.f, 0.f, 0.f, 0.f}, {0.f, 0.f, 0.f, 0.f}};

    int last_kb = blockIdx.x * 64;
    for (int kb = 0; kb <= last_kb; kb += 64) {
        __syncthreads();
        // stage K tile (both halves): 64 rows x 128 bf16
        for (int c = tid; c < 1024; c += 256) {
            int rr = c >> 4, cc = c & 15;
            short8 val = *(const short8*)(kbuf +
                ((long)(b * S_ + kb + rr) * KV_ + kv) * 128 + cc * 8);
            if (cc < 8) *(short8*)&k1s[rr][cc * 8] = val;
            else        *(short8*)&k2s[rr][(cc - 8) * 8] = val;
        }
        // stage V tile transposed
        for (int c = tid; c < 512; c += 256) {
            int rr = c >> 3, d0 = (c & 7) * 8;
            short8 val = *(const short8*)(vbuf +
                ((long)(b * S_ + kb + rr) * KV_ + kv) * 64 + d0);
#pragma unroll
            for (int e = 0; e < 8; ++e) vts[d0 + e][rr] = val[e];
        }
        __syncthreads();

        bool domask = (kb == last_kb);
#pragma unroll
        for (int m = 0; m < 2; ++m) {
            const short (*ks)[72] = m ? k2s : k1s;
            // S = Q @ K^T : 4 col-tiles x 2 k-steps
            floatx4 sacc[4];
#pragma unroll
            for (int nt = 0; nt < 4; ++nt) {
                sacc[nt] = {0.f, 0.f, 0.f, 0.f};
                short8 b0 = *(const short8*)&ks[nt * 16 + r][kq * 8];
                short8 b1 = *(const short8*)&ks[nt * 16 + r][32 + kq * 8];
                sacc[nt] = __builtin_amdgcn_mfma_f32_16x16x32_bf16(qa[m][0], b0, sacc[nt], 0, 0, 0);
                sacc[nt] = __builtin_amdgcn_mfma_f32_16x16x32_bf16(qa[m][1], b1, sacc[nt], 0, 0, 0);
            }
            // softcap + exp(s - 12) + mask; C layout: row=kq*4+j, col=nt*16+r
#pragma unroll
            for (int nt = 0; nt < 4; ++nt) {
#pragma unroll
                for (int j = 0; j < 4; ++j) {
                    float raw = sacc[nt][j];
                    // cap = 50*tanh(raw*0.125/50); tanh via e^{2x}
                    float ex = __expf(raw * 0.005f);
                    float cap = 50.f * __fdividef(ex - 1.f, ex + 1.f);
                    float p = __expf(cap - 12.f);
                    if (domask && (kb + nt * 16 + r > q0 + kq * 4 + j)) p = 0.f;
                    lp[m][j] += p;
                    pls[w][kq * 4 + j][nt * 16 + r] =
                        __builtin_bit_cast(short, __float2bfloat16(p));
                }
            }
            // PV: A-frag = P rows (wave-private LDS), B-frag = V^T rows
            short8 pa0 = *(const short8*)&pls[w][r][kq * 8];
            short8 pa1 = *(const short8*)&pls[w][r][32 + kq * 8];
#pragma unroll
            for (int dt = 0; dt < 4; ++dt) {
                short8 vb0 = *(const short8*)&vts[dt * 16 + r][kq * 8];
                short8 vb1 = *(const short8*)&vts[dt * 16 + r][32 + kq * 8];
                acc[m][dt] = __builtin_amdgcn_mfma_f32_16x16x32_bf16(pa0, vb0, acc[m][dt], 0, 0, 0);
                acc[m][dt] = __builtin_amdgcn_mfma_f32_16x16x32_bf16(pa1, vb1, acc[m][dt], 0, 0, 0);
            }
        }
    }

    // reduce row-sums across the 16-lane col groups
#pragma unroll
    for (int m = 0; m < 2; ++m)
#pragma unroll
        for (int j = 0; j < 4; ++j)
#pragma unroll
            for (int off = 8; off; off >>= 1)
                lp[m][j] += __shfl_xor(lp[m][j], off);

    // epilogue: out = O1/l1 - lam*O2/l2, write bf16
#pragma unroll
    for (int j = 0; j < 4; ++j) {
        float i1 = 1.f / lp[0][j];
        float i2 = lam / lp[1][j];
        int qr = q0 + kq * 4 + j;
        __hip_bfloat16* orow = ob + ((long)(b * S_ + qr) * H_ + h) * 64;
#pragma unroll
        for (int dt = 0; dt < 4; ++dt) {
            float val = acc[0][dt][j] * i1 - acc[1][dt][j] * i2;
            orow[dt * 16 + r] = __float2bfloat16(val);
        }
    }
}

// ---------------- launch ----------------
extern "C" void kernel_launch(void* const* d_in, const int* in_sizes, int n_in,
                              void* d_out, int out_size, void* d_ws, size_t ws_size,
                              hipStream_t stream) {
    const float* x     = (const float*)d_in[0];
    const float* freqs = (const float*)d_in[1];
    const float* wq    = (const float*)d_in[2];
    const float* wk    = (const float*)d_in[3];
    const float* wv    = (const float*)d_in[4];
    const float* wo    = (const float*)d_in[5];
    const float* qnw   = (const float*)d_in[6];
    const float* knw   = (const float*)d_in[7];
    const float* lam   = (const float*)d_in[8];
    float* out = (float*)d_out;

    const int T = B_ * S_;
    char* ws = (char*)d_ws;
    size_t off = 0;
    auto alloc = [&](size_t bytes) {
        void* p = ws + off;
        off += (bytes + 255) & ~(size_t)255;
        return p;
    };
    __hip_bfloat16* xb  = (__hip_bfloat16*)alloc((size_t)T * D_ * 2);
    __hip_bfloat16* wqb = (__hip_bfloat16*)alloc((size_t)2 * H_ * HD_ * D_ * 2);
    __hip_bfloat16* wkb = (__hip_bfloat16*)alloc((size_t)2 * KV_ * HD_ * D_ * 2);
    __hip_bfloat16* wvb = (__hip_bfloat16*)alloc((size_t)KV_ * HD_ * D_ * 2);
    __hip_bfloat16* wob = (__hip_bfloat16*)alloc((size_t)D_ * H_ * HD_ * 2);
    float* qf = (float*)alloc((size_t)T * 2 * H_ * HD_ * 4);
    float* kf = (float*)alloc((size_t)T * 2 * KV_ * HD_ * 4);
    float* vf = (float*)alloc((size_t)T * KV_ * HD_ * 4);
    __hip_bfloat16* qb16 = (__hip_bfloat16*)alloc((size_t)T * 2 * H_ * HD_ * 2);
    __hip_bfloat16* kb16 = (__hip_bfloat16*)alloc((size_t)T * 2 * KV_ * HD_ * 2);
    __hip_bfloat16* vb16 = (__hip_bfloat16*)alloc((size_t)T * KV_ * HD_ * 2);
    __hip_bfloat16* aob  = (__hip_bfloat16*)alloc((size_t)T * H_ * HD_ * 2);

    auto cvt = [&](const float* src, __hip_bfloat16* dst, int n) {
        cvt_bf16_kernel<<<(n + 255) / 256, 256, 0, stream>>>(src, dst, n);
    };
    cvt(x, xb, T * D_);
    cvt(wq, wqb, 2 * H_ * HD_ * D_);
    cvt(wk, wkb, 2 * KV_ * HD_ * D_);
    cvt(wv, wvb, KV_ * HD_ * D_);
    cvt(wo, wob, D_ * H_ * HD_);

    // projections (f32 out for q,k; v straight to bf16 after)
    gemm_bt_kernel<<<dim3((2 * H_ * HD_) / 128, T / 128), 256, 0, stream>>>(
        (const short*)xb, (const short*)wqb, qf, T, 2 * H_ * HD_, D_);
    gemm_bt_kernel<<<dim3((2 * KV_ * HD_) / 128, T / 128), 256, 0, stream>>>(
        (const short*)xb, (const short*)wkb, kf, T, 2 * KV_ * HD_, D_);
    gemm_bt_kernel<<<dim3((KV_ * HD_) / 128, T / 128), 256, 0, stream>>>(
        (const short*)xb, (const short*)wvb, vf, T, KV_ * HD_, D_);

    // QK-norm + RoPE -> bf16; V -> bf16
    {
        int nvq = T * H_ * 2;
        norm_rope_kernel<<<(nvq * 64 + 255) / 256, 256, 0, stream>>>(qf, qb16, freqs, qnw, nvq, H_);
        int nvk = T * KV_ * 2;
        norm_rope_kernel<<<(nvk * 64 + 255) / 256, 256, 0, stream>>>(kf, kb16, freqs, knw, nvk, KV_);
        cvt(vf, vb16, T * KV_ * HD_);
    }

    // differential causal attention (MFMA)
    attn_kernel<<<dim3(S_ / 64, H_, B_), 256, 0, stream>>>(
        (const short*)qb16, (const short*)kb16, (const short*)vb16, aob, lam);

    // output projection
    gemm_bt_kernel<<<dim3(D_ / 128, T / 128), 256, 0, stream>>>(
        (const short*)aob, (const short*)wob, out, T, D_, D_);
}

// Round 3
// 279.535 us; speedup vs baseline: 9.9417x; 1.7027x over previous
//
#include <hip/hip_runtime.h>
#include <hip/hip_bf16.h>

#define B_ 2
#define S_ 2048
#define D_ 1024
#define H_ 16
#define KV_ 4
#define HD_ 64
#define G_ (H_ / KV_)
#define NCAT 2816          // 2*H*HD + 2*KV*HD + KV*HD
#define VOFF 2560          // col offset of V block in fused QKV output

typedef __attribute__((ext_vector_type(8))) short short8;
typedef __attribute__((ext_vector_type(4))) float floatx4;

using gvoid_p = const __attribute__((address_space(1))) void*;
using lvoid_p = __attribute__((address_space(3))) void*;

__device__ inline void gload_lds16(const short* g, short* l) {
    __builtin_amdgcn_global_load_lds((gvoid_p)(const void*)g, (lvoid_p)(void*)l, 16, 0, 0);
}

// ---------------- fp32 -> bf16 convert ----------------
__global__ void cvt_bf16_kernel(const float* __restrict__ in,
                                __hip_bfloat16* __restrict__ out, int n) {
    int i = blockIdx.x * blockDim.x + threadIdx.x;
    if (i < n) out[i] = __float2bfloat16(in[i]);
}

// ---------------- NT GEMM with LDS staging (m97 structure) ----------------
// C(MxN) f32 = A(MxK) * B(NxK)^T, bf16 inputs. 128x128 block tile, BK=32,
// 4 waves (2x2), 4x4 16x16x32 MFMA per wave. global_load_lds width 16.
__global__ __launch_bounds__(256) void gemm_bt_lds(const short* __restrict__ A,
                                                   const short* __restrict__ Bm,
                                                   float* __restrict__ C,
                                                   int M, int N, int K) {
    __shared__ __align__(16) short As[128 * 32];
    __shared__ __align__(16) short Bs[128 * 32];
    int tid = threadIdx.x;
    int wid = tid >> 6, lane = tid & 63;
    int wr = wid >> 1, wc = wid & 1;
    int r = lane & 15, kq = lane >> 4;
    long m0 = (long)blockIdx.y * 128;
    long n0 = (long)blockIdx.x * 128;

    // staging: 512 chunks of 16B per tile; thread t covers chunks t and 256+t.
    // chunk c -> row c>>2, in-row 16B slot c&3. LDS dest is linear (chunk c at byte c*16).
    const short* gA0 = A + (m0 + (tid >> 2)) * (long)K + (tid & 3) * 8;
    const short* gA1 = A + (m0 + 64 + (tid >> 2)) * (long)K + (tid & 3) * 8;
    const short* gB0 = Bm + (n0 + (tid >> 2)) * (long)K + (tid & 3) * 8;
    const short* gB1 = Bm + (n0 + 64 + (tid >> 2)) * (long)K + (tid & 3) * 8;
    short* lA0 = As + (wid * 64) * 8;          // wave-uniform LDS bases
    short* lA1 = As + (256 + wid * 64) * 8;
    short* lB0 = Bs + (wid * 64) * 8;
    short* lB1 = Bs + (256 + wid * 64) * 8;

    floatx4 acc[4][4];
#pragma unroll
    for (int i = 0; i < 4; ++i)
#pragma unroll
        for (int j = 0; j < 4; ++j) acc[i][j] = {0.f, 0.f, 0.f, 0.f};

    for (int k0 = 0; k0 < K; k0 += 32) {
        __syncthreads();
        gload_lds16(gA0 + k0, lA0);
        gload_lds16(gA1 + k0, lA1);
        gload_lds16(gB0 + k0, lB0);
        gload_lds16(gB1 + k0, lB1);
        __syncthreads();
        short8 a[4], b[4];
#pragma unroll
        for (int mi = 0; mi < 4; ++mi)
            a[mi] = *(const short8*)&As[(wr * 64 + mi * 16 + r) * 32 + kq * 8];
#pragma unroll
        for (int ni = 0; ni < 4; ++ni)
            b[ni] = *(const short8*)&Bs[(wc * 64 + ni * 16 + r) * 32 + kq * 8];
#pragma unroll
        for (int mi = 0; mi < 4; ++mi)
#pragma unroll
            for (int ni = 0; ni < 4; ++ni)
                acc[mi][ni] = __builtin_amdgcn_mfma_f32_16x16x32_bf16(
                    a[mi], b[ni], acc[mi][ni], 0, 0, 0);
    }
    int col_l = lane & 15, row_l = (lane >> 4) * 4;
#pragma unroll
    for (int mi = 0; mi < 4; ++mi)
#pragma unroll
        for (int ni = 0; ni < 4; ++ni) {
            long col = n0 + wc * 64 + ni * 16 + col_l;
            long row0 = m0 + wr * 64 + mi * 16 + row_l;
#pragma unroll
            for (int j = 0; j < 4; ++j)
                C[(row0 + j) * N + col] = acc[mi][ni][j];
        }
}

// ---------------- RMSNorm (per-64) + RoPE, strided f32 in -> packed bf16 out ----------------
__global__ void norm_rope_kernel(const float* __restrict__ buf,
                                 __hip_bfloat16* __restrict__ outb,
                                 const float* __restrict__ freqs,
                                 const float* __restrict__ w, int nvec, int nh,
                                 int tstride, int colbase) {
    int gt = blockIdx.x * blockDim.x + threadIdx.x;
    int gw = gt >> 6;
    int lane = gt & 63;
    if (gw >= nvec) return;
    int t = gw / (nh * 2);
    int rem = gw - t * (nh * 2);
    int s = t & (S_ - 1);
    const float* v = buf + (long)t * tstride + colbase + rem * 64;
    float x = v[lane];
    float ss = x * x;
#pragma unroll
    for (int off = 32; off; off >>= 1) ss += __shfl_xor(ss, off);
    float r = rsqrtf(ss * (1.f / 64.f) + 1e-6f);
    x = x * r * w[lane];
    int i = lane >> 1;
    float c  = freqs[(s * (HD_ / 2) + i) * 2];
    float sn = freqs[(s * (HD_ / 2) + i) * 2 + 1];
    float p = __shfl_xor(x, 1);
    float y = (lane & 1) ? fmaf(p, sn, x * c) : fmaf(x, c, -(p * sn));
    outb[(long)gw * 64 + lane] = __float2bfloat16(y);
}

// ---------------- V transpose: qkvf f32 [t][NCAT] -> vT bf16 [b][kv][d][s] ----------------
__global__ __launch_bounds__(256) void v_transpose_kernel(const float* __restrict__ src,
                                                          __hip_bfloat16* __restrict__ dst) {
    __shared__ float ls[64][65];
    int s0 = blockIdx.x * 64;
    int kv = blockIdx.y, b = blockIdx.z;
    int tid = threadIdx.x;
    const float* base = src + ((long)(b * S_ + s0)) * NCAT + VOFF + kv * 64;
#pragma unroll
    for (int i = 0; i < 16; ++i) {
        int idx = i * 256 + tid;
        int sl = idx >> 6, d = idx & 63;
        ls[sl][d] = base[(long)sl * NCAT + d];
    }
    __syncthreads();
    __hip_bfloat16* ob = dst + ((long)(b * KV_ + kv) * 64) * S_ + s0;
#pragma unroll
    for (int i = 0; i < 16; ++i) {
        int idx = i * 256 + tid;
        int d = idx >> 6, sl = idx & 63;
        ob[(long)d * S_ + sl] = __float2bfloat16(ls[sl][d]);
    }
}

// ---------------- differential causal attention (MFMA flash) ----------------
// grid (S/64, H, B) with LONGEST-FIRST q-tile mapping; block 256 = 4 waves,
// wave w owns q rows [qt*64+w*16, +16). Fixed-offset softmax (|cap|<=8):
// p = exp2(poly(raw) - 12*log2e); row-sum via all-ones PV MFMA column.
__global__ __launch_bounds__(256) void attn_kernel(const short* __restrict__ qb,
                                                   const short* __restrict__ kbuf,
                                                   const short* __restrict__ vtb,
                                                   __hip_bfloat16* __restrict__ ob,
                                                   const float* __restrict__ lam_p) {
    __shared__ __align__(16) short k1s[64][72];
    __shared__ __align__(16) short k2s[64][72];
    __shared__ __align__(16) short vts[64][72];   // V^T tile: [d][k]
    __shared__ __align__(16) short pls[4][16][72];

    int tid = threadIdx.x, w = tid >> 6, lane = tid & 63;
    int b = blockIdx.z, h = blockIdx.y, kv = h / G_;
    int qt = (int)(gridDim.x - 1 - blockIdx.x);   // longest-first
    int q0 = qt * 64 + w * 16;
    int r = lane & 15, kq = lane >> 4;
    float lam = lam_p[0];

    short8 qa[2][2];
    {
        const short* qrow = qb + ((long)(b * S_ + q0 + r) * H_ + h) * 128;
        qa[0][0] = *(const short8*)(qrow + kq * 8);
        qa[0][1] = *(const short8*)(qrow + 32 + kq * 8);
        qa[1][0] = *(const short8*)(qrow + 64 + kq * 8);
        qa[1][1] = *(const short8*)(qrow + 96 + kq * 8);
    }

    floatx4 acc[2][4];
    floatx4 accl[2];   // row-sums via ones-column MFMA
#pragma unroll
    for (int m = 0; m < 2; ++m) {
        accl[m] = {0.f, 0.f, 0.f, 0.f};
#pragma unroll
        for (int dt = 0; dt < 4; ++dt) acc[m][dt] = {0.f, 0.f, 0.f, 0.f};
    }
    const short one_bf = (short)0x3F80;
    short8 ones = {one_bf, one_bf, one_bf, one_bf, one_bf, one_bf, one_bf, one_bf};

    const short* vbase = vtb + (long)(b * KV_ + kv) * 64 * S_;
    // softcap+softmax constants: t = raw*0.125*log2e; z = t*(1 - c2 t^2 + c3 t^4) - 12*log2e
    const float c1 = 0.18033688f, c2 = 6.40607e-5f, c3 = 4.9243e-9f, zoff = -17.3123405f;

    int last_kb = qt * 64;
    for (int kb = 0; kb <= last_kb; kb += 64) {
        __syncthreads();
        for (int c = tid; c < 1024; c += 256) {
            int rr = c >> 4, cc = c & 15;
            short8 val = *(const short8*)(kbuf +
                ((long)(b * S_ + kb + rr) * KV_ + kv) * 128 + cc * 8);
            if (cc < 8) *(short8*)&k1s[rr][cc * 8] = val;
            else        *(short8*)&k2s[rr][(cc - 8) * 8] = val;
        }
        for (int c = tid; c < 512; c += 256) {
            int rr = c >> 3, cc = c & 7;
            *(short8*)&vts[rr][cc * 8] =
                *(const short8*)(vbase + (long)rr * S_ + kb + cc * 8);
        }
        __syncthreads();

        bool domask = (kb == last_kb);
#pragma unroll
        for (int m = 0; m < 2; ++m) {
            const short (*ks)[72] = m ? k2s : k1s;
            floatx4 sacc[4];
#pragma unroll
            for (int nt = 0; nt < 4; ++nt) {
                sacc[nt] = {0.f, 0.f, 0.f, 0.f};
                short8 b0 = *(const short8*)&ks[nt * 16 + r][kq * 8];
                short8 b1 = *(const short8*)&ks[nt * 16 + r][32 + kq * 8];
                sacc[nt] = __builtin_amdgcn_mfma_f32_16x16x32_bf16(qa[m][0], b0, sacc[nt], 0, 0, 0);
                sacc[nt] = __builtin_amdgcn_mfma_f32_16x16x32_bf16(qa[m][1], b1, sacc[nt], 0, 0, 0);
            }
#pragma unroll
            for (int nt = 0; nt < 4; ++nt) {
#pragma unroll
                for (int j = 0; j < 4; ++j) {
                    float t = sacc[nt][j] * c1;
                    float t2 = t * t;
                    float u = fmaf(c3, t2, -c2);
                    float wv = fmaf(u, t2, 1.0f);
                    float z = fmaf(t, wv, zoff);
                    float p = __builtin_amdgcn_exp2f(z);
                    if (domask && (kb + nt * 16 + r > q0 + kq * 4 + j)) p = 0.f;
                    pls[w][kq * 4 + j][nt * 16 + r] =
                        __builtin_bit_cast(short, __float2bfloat16(p));
                }
            }
            short8 pa0 = *(const short8*)&pls[w][r][kq * 8];
            short8 pa1 = *(const short8*)&pls[w][r][32 + kq * 8];
#pragma unroll
            for (int dt = 0; dt < 4; ++dt) {
                short8 vb0 = *(const short8*)&vts[dt * 16 + r][kq * 8];
                short8 vb1 = *(const short8*)&vts[dt * 16 + r][32 + kq * 8];
                acc[m][dt] = __builtin_amdgcn_mfma_f32_16x16x32_bf16(pa0, vb0, acc[m][dt], 0, 0, 0);
                acc[m][dt] = __builtin_amdgcn_mfma_f32_16x16x32_bf16(pa1, vb1, acc[m][dt], 0, 0, 0);
            }
            accl[m] = __builtin_amdgcn_mfma_f32_16x16x32_bf16(pa0, ones, accl[m], 0, 0, 0);
            accl[m] = __builtin_amdgcn_mfma_f32_16x16x32_bf16(pa1, ones, accl[m], 0, 0, 0);
        }
    }

#pragma unroll
    for (int j = 0; j < 4; ++j) {
        float i1 = 1.f / accl[0][j];
        float i2 = lam / accl[1][j];
        int qr = q0 + kq * 4 + j;
        __hip_bfloat16* orow = ob + ((long)(b * S_ + qr) * H_ + h) * 64;
#pragma unroll
        for (int dt = 0; dt < 4; ++dt) {
            float val = acc[0][dt][j] * i1 - acc[1][dt][j] * i2;
            orow[dt * 16 + r] = __float2bfloat16(val);
        }
    }
}

// ---------------- launch ----------------
extern "C" void kernel_launch(void* const* d_in, const int* in_sizes, int n_in,
                              void* d_out, int out_size, void* d_ws, size_t ws_size,
                              hipStream_t stream) {
    const float* x     = (const float*)d_in[0];
    const float* freqs = (const float*)d_in[1];
    const float* wq    = (const float*)d_in[2];
    const float* wk    = (const float*)d_in[3];
    const float* wv    = (const float*)d_in[4];
    const float* wo    = (const float*)d_in[5];
    const float* qnw   = (const float*)d_in[6];
    const float* knw   = (const float*)d_in[7];
    const float* lam   = (const float*)d_in[8];
    float* out = (float*)d_out;

    const int T = B_ * S_;
    char* ws = (char*)d_ws;
    size_t off = 0;
    auto alloc = [&](size_t bytes) {
        void* p = ws + off;
        off += (bytes + 255) & ~(size_t)255;
        return p;
    };
    __hip_bfloat16* xb   = (__hip_bfloat16*)alloc((size_t)T * D_ * 2);
    __hip_bfloat16* wcat = (__hip_bfloat16*)alloc((size_t)NCAT * D_ * 2);
    __hip_bfloat16* wob  = (__hip_bfloat16*)alloc((size_t)D_ * D_ * 2);
    float* qkvf = (float*)alloc((size_t)T * NCAT * 4);
    __hip_bfloat16* qb16 = (__hip_bfloat16*)alloc((size_t)T * 2 * H_ * HD_ * 2);
    __hip_bfloat16* kb16 = (__hip_bfloat16*)alloc((size_t)T * 2 * KV_ * HD_ * 2);
    __hip_bfloat16* vT   = (__hip_bfloat16*)alloc((size_t)B_ * KV_ * HD_ * S_ * 2);
    __hip_bfloat16* aob  = xb;   // xb dead after QKV GEMM; same size

    auto cvt = [&](const float* src, __hip_bfloat16* dst, long n) {
        cvt_bf16_kernel<<<(n + 255) / 256, 256, 0, stream>>>(src, dst, (int)n);
    };
    cvt(x, xb, (long)T * D_);
    cvt(wq, wcat, (long)2 * H_ * HD_ * D_);
    cvt(wk, wcat + (size_t)2 * H_ * HD_ * D_, (long)2 * KV_ * HD_ * D_);
    cvt(wv, wcat + (size_t)(2 * H_ * HD_ + 2 * KV_ * HD_) * D_, (long)KV_ * HD_ * D_);
    cvt(wo, wob, (long)D_ * D_);

    // fused QKV projection: [T x NCAT] = xb @ wcat^T
    gemm_bt_lds<<<dim3(NCAT / 128, T / 128), 256, 0, stream>>>(
        (const short*)xb, (const short*)wcat, qkvf, T, NCAT, D_);

    // QK-norm + RoPE -> bf16 (packed); V -> transposed bf16
    {
        int nvq = T * H_ * 2;
        norm_rope_kernel<<<(nvq * 64 + 255) / 256, 256, 0, stream>>>(
            qkvf, qb16, freqs, qnw, nvq, H_, NCAT, 0);
        int nvk = T * KV_ * 2;
        norm_rope_kernel<<<(nvk * 64 + 255) / 256, 256, 0, stream>>>(
            qkvf, kb16, freqs, knw, nvk, KV_, NCAT, 2 * H_ * HD_);
        v_transpose_kernel<<<dim3(S_ / 64, KV_, B_), 256, 0, stream>>>(qkvf, vT);
    }

    // differential causal attention
    attn_kernel<<<dim3(S_ / 64, H_, B_), 256, 0, stream>>>(
        (const short*)qb16, (const short*)kb16, (const short*)vT, aob, lam);

    // output projection
    gemm_bt_lds<<<dim3(D_ / 128, T / 128), 256, 0, stream>>>(
        (const short*)aob, (const short*)wob, out, T, D_, D_);
}

// Round 4
// 248.250 us; speedup vs baseline: 11.1946x; 1.1260x over previous
//
#include <hip/hip_runtime.h>
#include <hip/hip_bf16.h>

#define B_ 2
#define S_ 2048
#define D_ 1024
#define H_ 16
#define KV_ 4
#define HD_ 64
#define G_ (H_ / KV_)
#define NCAT 2816          // 2*H*HD + 2*KV*HD + KV*HD
#define VOFF 2560          // col offset of V block in fused QKV output

typedef __attribute__((ext_vector_type(8))) short short8;
typedef __attribute__((ext_vector_type(4))) short short4v;
typedef __attribute__((ext_vector_type(4))) float floatx4;

using gvoid_p = const __attribute__((address_space(1))) void*;
using lvoid_p = __attribute__((address_space(3))) void*;

__device__ inline void gload_lds16(const short* g, short* l) {
    __builtin_amdgcn_global_load_lds((gvoid_p)(const void*)g, (lvoid_p)(void*)l, 16, 0, 0);
}

// pack two f32 -> one dword of two bf16 (T12 recipe: no builtin on gfx950)
__device__ inline int cvt_pk_bf16(float lo, float hi) {
    int r;
    asm volatile("v_cvt_pk_bf16_f32 %0, %1, %2" : "=v"(r) : "v"(lo), "v"(hi));
    return r;
}

// ---------------- fp32 -> bf16 convert ----------------
__global__ void cvt_bf16_kernel(const float* __restrict__ in,
                                __hip_bfloat16* __restrict__ out, int n) {
    int i = blockIdx.x * blockDim.x + threadIdx.x;
    if (i < n) out[i] = __float2bfloat16(in[i]);
}

// ---------------- NT GEMM with LDS staging (m97 structure) ----------------
__global__ __launch_bounds__(256) void gemm_bt_lds(const short* __restrict__ A,
                                                   const short* __restrict__ Bm,
                                                   float* __restrict__ C,
                                                   int M, int N, int K) {
    __shared__ __align__(16) short As[128 * 32];
    __shared__ __align__(16) short Bs[128 * 32];
    int tid = threadIdx.x;
    int wid = tid >> 6, lane = tid & 63;
    int wr = wid >> 1, wc = wid & 1;
    int r = lane & 15, kq = lane >> 4;
    long m0 = (long)blockIdx.y * 128;
    long n0 = (long)blockIdx.x * 128;

    const short* gA0 = A + (m0 + (tid >> 2)) * (long)K + (tid & 3) * 8;
    const short* gA1 = A + (m0 + 64 + (tid >> 2)) * (long)K + (tid & 3) * 8;
    const short* gB0 = Bm + (n0 + (tid >> 2)) * (long)K + (tid & 3) * 8;
    const short* gB1 = Bm + (n0 + 64 + (tid >> 2)) * (long)K + (tid & 3) * 8;
    short* lA0 = As + (wid * 64) * 8;
    short* lA1 = As + (256 + wid * 64) * 8;
    short* lB0 = Bs + (wid * 64) * 8;
    short* lB1 = Bs + (256 + wid * 64) * 8;

    floatx4 acc[4][4];
#pragma unroll
    for (int i = 0; i < 4; ++i)
#pragma unroll
        for (int j = 0; j < 4; ++j) acc[i][j] = {0.f, 0.f, 0.f, 0.f};

    for (int k0 = 0; k0 < K; k0 += 32) {
        __syncthreads();
        gload_lds16(gA0 + k0, lA0);
        gload_lds16(gA1 + k0, lA1);
        gload_lds16(gB0 + k0, lB0);
        gload_lds16(gB1 + k0, lB1);
        __syncthreads();
        short8 a[4], b[4];
#pragma unroll
        for (int mi = 0; mi < 4; ++mi)
            a[mi] = *(const short8*)&As[(wr * 64 + mi * 16 + r) * 32 + kq * 8];
#pragma unroll
        for (int ni = 0; ni < 4; ++ni)
            b[ni] = *(const short8*)&Bs[(wc * 64 + ni * 16 + r) * 32 + kq * 8];
#pragma unroll
        for (int mi = 0; mi < 4; ++mi)
#pragma unroll
            for (int ni = 0; ni < 4; ++ni)
                acc[mi][ni] = __builtin_amdgcn_mfma_f32_16x16x32_bf16(
                    a[mi], b[ni], acc[mi][ni], 0, 0, 0);
    }
    int col_l = lane & 15, row_l = (lane >> 4) * 4;
#pragma unroll
    for (int mi = 0; mi < 4; ++mi)
#pragma unroll
        for (int ni = 0; ni < 4; ++ni) {
            long col = n0 + wc * 64 + ni * 16 + col_l;
            long row0 = m0 + wr * 64 + mi * 16 + row_l;
#pragma unroll
            for (int j = 0; j < 4; ++j)
                C[(row0 + j) * N + col] = acc[mi][ni][j];
        }
}

// ---------------- RMSNorm (per-64) + RoPE, strided f32 in -> packed bf16 out ----------------
__global__ void norm_rope_kernel(const float* __restrict__ buf,
                                 __hip_bfloat16* __restrict__ outb,
                                 const float* __restrict__ freqs,
                                 const float* __restrict__ w, int nvec, int nh,
                                 int tstride, int colbase) {
    int gt = blockIdx.x * blockDim.x + threadIdx.x;
    int gw = gt >> 6;
    int lane = gt & 63;
    if (gw >= nvec) return;
    int t = gw / (nh * 2);
    int rem = gw - t * (nh * 2);
    int s = t & (S_ - 1);
    const float* v = buf + (long)t * tstride + colbase + rem * 64;
    float x = v[lane];
    float ss = x * x;
#pragma unroll
    for (int off = 32; off; off >>= 1) ss += __shfl_xor(ss, off);
    float r = rsqrtf(ss * (1.f / 64.f) + 1e-6f);
    x = x * r * w[lane];
    int i = lane >> 1;
    float c  = freqs[(s * (HD_ / 2) + i) * 2];
    float sn = freqs[(s * (HD_ / 2) + i) * 2 + 1];
    float p = __shfl_xor(x, 1);
    float y = (lane & 1) ? fmaf(p, sn, x * c) : fmaf(x, c, -(p * sn));
    outb[(long)gw * 64 + lane] = __float2bfloat16(y);
}

// ---------------- V transpose: qkvf f32 [t][NCAT] -> vT bf16 [b][kv][d][s] ----------------
__global__ __launch_bounds__(256) void v_transpose_kernel(const float* __restrict__ src,
                                                          __hip_bfloat16* __restrict__ dst) {
    __shared__ float ls[64][65];
    int s0 = blockIdx.x * 64;
    int kv = blockIdx.y, b = blockIdx.z;
    int tid = threadIdx.x;
    const float* base = src + ((long)(b * S_ + s0)) * NCAT + VOFF + kv * 64;
#pragma unroll
    for (int i = 0; i < 16; ++i) {
        int idx = i * 256 + tid;
        int sl = idx >> 6, d = idx & 63;
        ls[sl][d] = base[(long)sl * NCAT + d];
    }
    __syncthreads();
    __hip_bfloat16* ob = dst + ((long)(b * KV_ + kv) * 64) * S_ + s0;
#pragma unroll
    for (int i = 0; i < 16; ++i) {
        int idx = i * 256 + tid;
        int d = idx >> 6, sl = idx & 63;
        ob[(long)d * S_ + sl] = __float2bfloat16(ls[sl][d]);
    }
}

// ---------------- differential causal attention (MFMA flash, swapped-QK, in-reg P) ----------------
// grid (32, H, B); qt = x ^ (31*((h>>3)^b)) gives every CU exactly 66 k-tile-units.
// Swapped QK^T: sacc = mfma(K_frag, Q_frag) = S^T; lane (r,kq) holds P[q=r][k=16nt+4kq+j]
// which IS the 16x16x16 A-fragment layout -> PV via mfma_f32_16x16x16_bf16, no LDS P.
// Fixed-offset softmax (|cap|<=8): p = exp2(poly(raw) - 12*log2e); l = lane-local f32 sum.
__global__ __launch_bounds__(256) void attn_kernel(const short* __restrict__ qb,
                                                   const short* __restrict__ kbuf,
                                                   const short* __restrict__ vtb,
                                                   __hip_bfloat16* __restrict__ ob,
                                                   const float* __restrict__ lam_p) {
    __shared__ __align__(16) short k1s[64][72];
    __shared__ __align__(16) short k2s[64][72];
    __shared__ __align__(16) short vts[64][76];   // V^T tile: [d][k], pad 76 (odd dword stride)

    int tid = threadIdx.x, w = tid >> 6, lane = tid & 63;
    int b = blockIdx.z, h = blockIdx.y, kv = h / G_;
    int qt = (int)blockIdx.x ^ (31 * (((h >> 3) ^ b) & 1));   // balanced mapping
    int q0 = qt * 64 + w * 16;
    int r = lane & 15, kq = lane >> 4;
    float lam = lam_p[0];

    short8 qa[2][2];
    {
        const short* qrow = qb + ((long)(b * S_ + q0 + r) * H_ + h) * 128;
        qa[0][0] = *(const short8*)(qrow + kq * 8);
        qa[0][1] = *(const short8*)(qrow + 32 + kq * 8);
        qa[1][0] = *(const short8*)(qrow + 64 + kq * 8);
        qa[1][1] = *(const short8*)(qrow + 96 + kq * 8);
    }

    floatx4 acc[2][4];
#pragma unroll
    for (int m = 0; m < 2; ++m)
#pragma unroll
        for (int dt = 0; dt < 4; ++dt) acc[m][dt] = {0.f, 0.f, 0.f, 0.f};
    float lsum[2] = {0.f, 0.f};

    const short* vbase = vtb + (long)(b * KV_ + kv) * 64 * S_;
    const float c1 = 0.18033688f, c2 = 6.40607e-5f, c3 = 4.9243e-9f, zoff = -17.3123405f;

    int last_kb = qt * 64;
    for (int kb = 0; kb <= last_kb; kb += 64) {
        __syncthreads();
        for (int c = tid; c < 1024; c += 256) {
            int rr = c >> 4, cc = c & 15;
            short8 val = *(const short8*)(kbuf +
                ((long)(b * S_ + kb + rr) * KV_ + kv) * 128 + cc * 8);
            if (cc < 8) *(short8*)&k1s[rr][cc * 8] = val;
            else        *(short8*)&k2s[rr][(cc - 8) * 8] = val;
        }
        for (int c = tid; c < 512; c += 256) {
            int rr = c >> 3, cc = c & 7;
            *(short8*)&vts[rr][cc * 8] =
                *(const short8*)(vbase + (long)rr * S_ + kb + cc * 8);
        }
        __syncthreads();

        bool domask = (kb == last_kb);
#pragma unroll
        for (int m = 0; m < 2; ++m) {
            const short (*ks)[72] = m ? k2s : k1s;
            // S^T = K @ Q^T (contraction over d=64): lane holds col q=r, rows k=4kq+j per nt
            floatx4 sacc[4];
#pragma unroll
            for (int nt = 0; nt < 4; ++nt) {
                sacc[nt] = {0.f, 0.f, 0.f, 0.f};
                short8 a0 = *(const short8*)&ks[nt * 16 + r][kq * 8];
                short8 a1 = *(const short8*)&ks[nt * 16 + r][32 + kq * 8];
                sacc[nt] = __builtin_amdgcn_mfma_f32_16x16x32_bf16(a0, qa[m][0], sacc[nt], 0, 0, 0);
                sacc[nt] = __builtin_amdgcn_mfma_f32_16x16x32_bf16(a1, qa[m][1], sacc[nt], 0, 0, 0);
            }
            // softcap + exp + mask + pack to bf16 A-frags (k=16nt+4kq+j, q=q0+r)
            short4v pa[4];
#pragma unroll
            for (int nt = 0; nt < 4; ++nt) {
                float p[4];
#pragma unroll
                for (int j = 0; j < 4; ++j) {
                    float t = sacc[nt][j] * c1;
                    float t2 = t * t;
                    float u = fmaf(c3, t2, -c2);
                    float wv = fmaf(u, t2, 1.0f);
                    float z = fmaf(t, wv, zoff);
                    p[j] = __builtin_amdgcn_exp2f(z);
                    if (domask && (kb + nt * 16 + kq * 4 + j > q0 + r)) p[j] = 0.f;
                    lsum[m] += p[j];
                }
                int lo = cvt_pk_bf16(p[0], p[1]);
                int hi = cvt_pk_bf16(p[2], p[3]);
                pa[nt][0] = (short)(lo & 0xffff);
                pa[nt][1] = (short)((unsigned)lo >> 16);
                pa[nt][2] = (short)(hi & 0xffff);
                pa[nt][3] = (short)((unsigned)hi >> 16);
            }
            // PV: O[q][d] += P[q][k16] * V^T[d][k16] per nt window, 16x16x16 MFMA
#pragma unroll
            for (int dt = 0; dt < 4; ++dt) {
#pragma unroll
                for (int nt = 0; nt < 4; ++nt) {
                    short4v vb = *(const short4v*)&vts[dt * 16 + r][16 * nt + 4 * kq];
                    acc[m][dt] = __builtin_amdgcn_mfma_f32_16x16x16bf16_1k(
                        pa[nt], vb, acc[m][dt], 0, 0, 0);
                }
            }
        }
    }

    // reduce l across the 4 kq lane-groups -> every lane holds L[q=r]
    float L0 = lsum[0], L1 = lsum[1];
    L0 += __shfl_xor(L0, 16); L0 += __shfl_xor(L0, 32);
    L1 += __shfl_xor(L1, 16); L1 += __shfl_xor(L1, 32);

    // epilogue: lane (r,kq) holds O[q=kq*4+j][d=dt*16+r]
#pragma unroll
    for (int j = 0; j < 4; ++j) {
        float i1 = 1.f / __shfl(L0, kq * 4 + j);
        float i2 = lam / __shfl(L1, kq * 4 + j);
        int qr = q0 + kq * 4 + j;
        __hip_bfloat16* orow = ob + ((long)(b * S_ + qr) * H_ + h) * 64;
#pragma unroll
        for (int dt = 0; dt < 4; ++dt) {
            float val = acc[0][dt][j] * i1 - acc[1][dt][j] * i2;
            orow[dt * 16 + r] = __float2bfloat16(val);
        }
    }
}

// ---------------- launch ----------------
extern "C" void kernel_launch(void* const* d_in, const int* in_sizes, int n_in,
                              void* d_out, int out_size, void* d_ws, size_t ws_size,
                              hipStream_t stream) {
    const float* x     = (const float*)d_in[0];
    const float* freqs = (const float*)d_in[1];
    const float* wq    = (const float*)d_in[2];
    const float* wk    = (const float*)d_in[3];
    const float* wv    = (const float*)d_in[4];
    const float* wo    = (const float*)d_in[5];
    const float* qnw   = (const float*)d_in[6];
    const float* knw   = (const float*)d_in[7];
    const float* lam   = (const float*)d_in[8];
    float* out = (float*)d_out;

    const int T = B_ * S_;
    char* ws = (char*)d_ws;
    size_t off = 0;
    auto alloc = [&](size_t bytes) {
        void* p = ws + off;
        off += (bytes + 255) & ~(size_t)255;
        return p;
    };
    __hip_bfloat16* xb   = (__hip_bfloat16*)alloc((size_t)T * D_ * 2);
    __hip_bfloat16* wcat = (__hip_bfloat16*)alloc((size_t)NCAT * D_ * 2);
    __hip_bfloat16* wob  = (__hip_bfloat16*)alloc((size_t)D_ * D_ * 2);
    float* qkvf = (float*)alloc((size_t)T * NCAT * 4);
    __hip_bfloat16* qb16 = (__hip_bfloat16*)alloc((size_t)T * 2 * H_ * HD_ * 2);
    __hip_bfloat16* kb16 = (__hip_bfloat16*)alloc((size_t)T * 2 * KV_ * HD_ * 2);
    __hip_bfloat16* vT   = (__hip_bfloat16*)alloc((size_t)B_ * KV_ * HD_ * S_ * 2);
    __hip_bfloat16* aob  = xb;   // xb dead after QKV GEMM; same size

    auto cvt = [&](const float* src, __hip_bfloat16* dst, long n) {
        cvt_bf16_kernel<<<(n + 255) / 256, 256, 0, stream>>>(src, dst, (int)n);
    };
    cvt(x, xb, (long)T * D_);
    cvt(wq, wcat, (long)2 * H_ * HD_ * D_);
    cvt(wk, wcat + (size_t)2 * H_ * HD_ * D_, (long)2 * KV_ * HD_ * D_);
    cvt(wv, wcat + (size_t)(2 * H_ * HD_ + 2 * KV_ * HD_) * D_, (long)KV_ * HD_ * D_);
    cvt(wo, wob, (long)D_ * D_);

    // fused QKV projection: [T x NCAT] = xb @ wcat^T
    gemm_bt_lds<<<dim3(NCAT / 128, T / 128), 256, 0, stream>>>(
        (const short*)xb, (const short*)wcat, qkvf, T, NCAT, D_);

    // QK-norm + RoPE -> bf16 (packed); V -> transposed bf16
    {
        int nvq = T * H_ * 2;
        norm_rope_kernel<<<(nvq * 64 + 255) / 256, 256, 0, stream>>>(
            qkvf, qb16, freqs, qnw, nvq, H_, NCAT, 0);
        int nvk = T * KV_ * 2;
        norm_rope_kernel<<<(nvk * 64 + 255) / 256, 256, 0, stream>>>(
            qkvf, kb16, freqs, knw, nvk, KV_, NCAT, 2 * H_ * HD_);
        v_transpose_kernel<<<dim3(S_ / 64, KV_, B_), 256, 0, stream>>>(qkvf, vT);
    }

    // differential causal attention
    attn_kernel<<<dim3(S_ / 64, H_, B_), 256, 0, stream>>>(
        (const short*)qb16, (const short*)kb16, (const short*)vT, aob, lam);

    // output projection
    gemm_bt_lds<<<dim3(D_ / 128, T / 128), 256, 0, stream>>>(
        (const short*)aob, (const short*)wob, out, T, D_, D_);
}